// Round 1
// 259.950 us; speedup vs baseline: 1.0366x; 1.0366x over previous
//
#include <hip/hip_runtime.h>
#include <hip/hip_bf16.h>

typedef __hip_bfloat16 bf16;

static __device__ __forceinline__ unsigned short f2us(float f) {
    union { float f; unsigned int i; } c; c.f = f;
    unsigned int r = c.i + 0x7FFF + ((c.i >> 16) & 1);   // round-to-nearest-even
    return (unsigned short)(r >> 16);
}

// wave-0 probe: is the float input stored as f32 (vs bf16)?
static __device__ __forceinline__ int probe_isf32(const unsigned short* xr, int* sflag) {
    int tid = threadIdx.x;
    if (tid < 64) {
        int bad = 0;
        for (int i = tid; i < 1024; i += 64) {
            int ex = (xr[2 * i] >> 7) & 0xFF;
            if (ex < 110 || ex > 135) bad++;
        }
#pragma unroll
        for (int m = 32; m >= 1; m >>= 1) bad += __shfl_xor(bad, m);
        if (tid == 0) *sflag = (bad > 256) ? 1 : 0;
    }
    __syncthreads();
    return *sflag;
}

static __device__ __forceinline__ int ld_edge(const int* er, size_t i, int idx64) {
    return idx64 ? er[2 * i] : er[i];
}

#define BSH 9
#define BMASK 511

// ---------------- canonicalization + Wcat pack + bcur zero (fused) ----------------
// x is NOT canonicalized anymore (l1_transform converts it inline); 18 segments = inputs i>=2.

struct CvtArgs { const void* p[18]; int sz[18]; };

static __device__ __forceinline__ float cvt_elem(const void* p, int off, int isf32) {
    return isf32 ? ((const float*)p)[off] : __bfloat162float(((const bf16*)p)[off]);
}

// blocks 0..nbconv-1: convert weight inputs to f32 canon.
// block nbconv: build Wcat[32][32] + bcat from raw inputs, zero bcur[0..511], write isf32 flag to bcur[512].
__global__ __launch_bounds__(256) void k_convert(CvtArgs a, const unsigned short* __restrict__ xraw,
                                                 float* __restrict__ dst, int total,
                                                 int nbconv, float* __restrict__ Wcat,
                                                 float* __restrict__ bcat, int* __restrict__ bcur) {
    __shared__ int sflag;
    int isf32 = probe_isf32(xraw, &sflag);
    int tid = threadIdx.x;
    if ((int)blockIdx.x == nbconv) {
        // p[10]=Wq p[11]=bq p[12]=Wk p[13]=bk p[14]=Wv p[15]=bv p[16]=Wskip p[17]=bskip
#pragma unroll
        for (int t4 = 0; t4 < 4; ++t4) {
            int idx = t4 * 256 + tid;           // 0..1023
            int c = idx & 31, g = c >> 3, cc = c & 7, kk = idx >> 5;
            const void* Wg = (g == 0) ? a.p[10] : (g == 1) ? a.p[16] : (g == 2) ? a.p[12] : a.p[14];
            Wcat[idx] = (cc < 7) ? cvt_elem(Wg, kk * 7 + cc, isf32) : 0.f;
        }
        if (tid < 32) {
            int g = tid >> 3, cc = tid & 7;
            const void* Bg = (g == 0) ? a.p[11] : (g == 1) ? a.p[17] : (g == 2) ? a.p[13] : a.p[15];
            bcat[tid] = (cc < 7) ? cvt_elem(Bg, cc, isf32) : 0.f;
        }
        bcur[tid] = 0;
        bcur[tid + 256] = 0;
        if (tid == 0) bcur[512] = isf32;
        return;
    }
    int t = blockIdx.x * 256 + tid;
    if (t >= total) return;
    int base = 0, seg = -1, off = 0;
#pragma unroll
    for (int i = 0; i < 18; i++) {
        if (seg < 0 && t < base + a.sz[i]) { seg = i; off = t - base; }
        base += a.sz[i];
    }
    dst[t] = cvt_elem(a.p[seg], off, isf32);
}

// ---------------- bucketed CSR build (512-node buckets; packed bkt) ----------------
// bucket b = dst >> 9; bkt entry = (src << 9) | (dst & 511)   [src < 2^18 -> 27 bits]

__global__ __launch_bounds__(1024) void k_bscatter(const int* __restrict__ er,
                                                   int* __restrict__ bcur, int* __restrict__ bkt,
                                                   int E, int NB, int C) {
    __shared__ int cnt[512];
    __shared__ int res[512];
    __shared__ int sflag;
    int tid = threadIdx.x;
    if (tid < 64) {
        int lim = (E < 1024) ? E : 1024;
        int nz = 0;
        for (int i = tid; i < lim; i += 64) if (er[2 * i + 1] != 0) nz++;
#pragma unroll
        for (int m = 32; m >= 1; m >>= 1) nz += __shfl_xor(nz, m);
        if (tid == 0) sflag = (nz < ((E < 1024 ? E : 1024) >> 1)) ? 1 : 0;
    }
    if (tid < 512) cnt[tid] = 0;
    __syncthreads();
    int idx64 = sflag;
    int e0 = blockIdx.x * 4096 + tid * 4;
    int sv[4], dv[4];
    bool val[4];
    bool fast = (e0 + 4 <= E) && ((E & 3) == 0);
    if (fast) {
        const int4* p4 = (const int4*)er;
        if (idx64) {
            int4 u0 = p4[e0 >> 1], u1 = p4[(e0 >> 1) + 1];
            int4 w0 = p4[(E + e0) >> 1], w1 = p4[((E + e0) >> 1) + 1];
            sv[0] = u0.x; sv[1] = u0.z; sv[2] = u1.x; sv[3] = u1.z;
            dv[0] = w0.x; dv[1] = w0.z; dv[2] = w1.x; dv[3] = w1.z;
        } else {
            int4 u = p4[e0 >> 2];
            int4 w = p4[(E + e0) >> 2];
            sv[0] = u.x; sv[1] = u.y; sv[2] = u.z; sv[3] = u.w;
            dv[0] = w.x; dv[1] = w.y; dv[2] = w.z; dv[3] = w.w;
        }
#pragma unroll
        for (int k = 0; k < 4; ++k) val[k] = true;
    } else {
#pragma unroll
        for (int k = 0; k < 4; ++k) {
            int e = e0 + k;
            val[k] = (e < E);
            if (val[k]) {
                sv[k] = ld_edge(er, (size_t)e, idx64);
                dv[k] = ld_edge(er, (size_t)E + e, idx64);
            }
        }
    }
    int pk[4], bv[4];
#pragma unroll
    for (int k = 0; k < 4; ++k) {
        if (val[k]) {
            bv[k] = dv[k] >> BSH;
            pk[k] = (sv[k] << BSH) | (dv[k] & BMASK);
            atomicAdd(&cnt[bv[k]], 1);
        }
    }
    __syncthreads();
    if (tid < NB) {
        int c = cnt[tid];
        res[tid] = c ? atomicAdd(&bcur[tid], c) : 0;
        cnt[tid] = 0;
    }
    __syncthreads();
#pragma unroll
    for (int k = 0; k < 4; ++k) {
        if (val[k]) {
            int r = res[bv[k]] + atomicAdd(&cnt[bv[k]], 1);
            if (r < C) bkt[(size_t)bv[k] * C + r] = pk[k];
        }
    }
}

// per bucket: indeg count + scan -> off2 (start,end); scatter src -> bucket-strided csr
__global__ __launch_bounds__(512) void k_bbuild(const int* __restrict__ bkt, const int* __restrict__ bcur,
                                                int2* __restrict__ off2, int* __restrict__ csr, int N, int C) {
    __shared__ int sm[512];
    int b = blockIdx.x, tid = threadIdx.x;
    size_t base = (size_t)b * C;
    int m = bcur[b]; if (m > C) m = C;
    sm[tid] = 0;
    __syncthreads();
    const int* bp = bkt + base;
    for (int i = tid; i < m; i += 512) atomicAdd(&sm[bp[i] & BMASK], 1);
    __syncthreads();
    int v = sm[tid];
    for (int d = 1; d < 512; d <<= 1) {
        int t = (tid >= d) ? sm[tid - d] : 0;
        __syncthreads();
        sm[tid] += t;
        __syncthreads();
    }
    int excl = sm[tid] - v;
    int node = (b << BSH) + tid;
    if (node < N) off2[node] = make_int2((int)base + excl, (int)base + excl + v);
    __syncthreads();
    sm[tid] = excl;
    __syncthreads();
    for (int i = tid; i < m; i += 512) {
        int p = bp[i];
        int r = atomicAdd(&sm[p & BMASK], 1);
        csr[base + r] = p >> BSH;
    }
}

// ---------------- Layer 1: GATConv(3, 16, heads=4) ----------------
// axs record per node: 32B = {a_src[4], x0, x1, x2, pad} -> edge gather touches ONE cache line.

__global__ __launch_bounds__(256) void k_l1_transform(const void* __restrict__ xr, const int* __restrict__ flagp,
                                                      const float* __restrict__ W1,
                                                      const float* __restrict__ att_s, const float* __restrict__ att_d,
                                                      float* __restrict__ axs, float* __restrict__ ad1, int N) {
    int tid = threadIdx.x;
    int node = blockIdx.x * 4 + (tid >> 6);
    if (node >= N) return;
    int lane = tid & 63;
    int isf32 = *flagp;
    float x0 = cvt_elem(xr, node * 3 + 0, isf32);
    float x1 = cvt_elem(xr, node * 3 + 1, isf32);
    float x2 = cvt_elem(xr, node * 3 + 2, isf32);
    float h = x0 * W1[lane] + x1 * W1[64 + lane] + x2 * W1[128 + lane];
    if (lane == 0) *(float4*)&axs[(size_t)node * 8 + 4] = make_float4(x0, x1, x2, 0.f);
    float ts = h * att_s[lane];
    float td = h * att_d[lane];
    for (int m = 8; m >= 1; m >>= 1) { ts += __shfl_xor(ts, m); td += __shfl_xor(td, m); }
    if ((lane & 15) == 0) {
        axs[(size_t)node * 8 + (lane >> 4)] = ts;
        ad1[node * 4 + (lane >> 4)] = td;
    }
}

// Edge-parallel: 16 lanes per node; accumulate per-head weighted x-3vec + denom, butterfly-reduce.
__global__ __launch_bounds__(256) void k_l1_agg(const float* __restrict__ axs,
                                                const float4* __restrict__ ad4p, const int2* __restrict__ off2,
                                                const int* __restrict__ csr, const float* __restrict__ W1,
                                                const float* __restrict__ b1,
                                                float* __restrict__ x1, int N) {
    int tid = threadIdx.x;
    int node = blockIdx.x * 16 + (tid >> 4);
    if (node >= N) return;
    int sl = tid & 15;
    int lane = tid & 63;
    int lb = lane & 48;

    float4 ad = ad4p[node];
    int2 ee = off2[node];
    int e0 = ee.x, e1 = ee.y;

    float v[16];
#pragma unroll
    for (int i = 0; i < 16; ++i) v[i] = 0.f;

    for (int jj = e0 + sl; jj < e1; jj += 16) {
        int s = csr[jj];
        const float4* rp = (const float4*)(axs + (size_t)s * 8);
        float4 a = rp[0];
        float4 xv = rp[1];
        float z0 = a.x + ad.x, z1 = a.y + ad.y, z2 = a.z + ad.z, z3 = a.w + ad.w;
        z0 = (z0 > 0.f) ? z0 : 0.2f * z0;
        z1 = (z1 > 0.f) ? z1 : 0.2f * z1;
        z2 = (z2 > 0.f) ? z2 : 0.2f * z2;
        z3 = (z3 > 0.f) ? z3 : 0.2f * z3;
        float w0 = __expf(z0), w1 = __expf(z1), w2 = __expf(z2), w3 = __expf(z3);
        v[0] += w0 * xv.x; v[1] += w0 * xv.y; v[2]  += w0 * xv.z; v[3]  += w0;
        v[4] += w1 * xv.x; v[5] += w1 * xv.y; v[6]  += w1 * xv.z; v[7]  += w1;
        v[8] += w2 * xv.x; v[9] += w2 * xv.y; v[10] += w2 * xv.z; v[11] += w2;
        v[12] += w3 * xv.x; v[13] += w3 * xv.y; v[14] += w3 * xv.z; v[15] += w3;
    }

#pragma unroll
    for (int d = 8; d >= 1; d >>= 1) {
#pragma unroll
        for (int i = 0; i < 16; ++i) {
            if (i < d) {
                float a = v[i], b = v[i + d];
                float send = (sl & d) ? a : b;
                float recv = __shfl_xor(send, d);
                v[i] = ((sl & d) ? b : a) + recv;
            }
        }
    }
    float r = v[0];

    float agx[4], agy[4], agz[4], dn[4];
#pragma unroll
    for (int h = 0; h < 4; ++h) {
        agx[h] = __shfl(r, lb + 4 * h + 0);
        agy[h] = __shfl(r, lb + 4 * h + 1);
        agz[h] = __shfl(r, lb + 4 * h + 2);
        dn[h]  = __shfl(r, lb + 4 * h + 3);
    }

    {
        const float4* rp = (const float4*)(axs + (size_t)node * 8);
        float4 a = rp[0];
        float4 xv = rp[1];
        float z0 = a.x + ad.x, z1 = a.y + ad.y, z2 = a.z + ad.z, z3 = a.w + ad.w;
        z0 = (z0 > 0.f) ? z0 : 0.2f * z0;
        z1 = (z1 > 0.f) ? z1 : 0.2f * z1;
        z2 = (z2 > 0.f) ? z2 : 0.2f * z2;
        z3 = (z3 > 0.f) ? z3 : 0.2f * z3;
        float w0 = __expf(z0), w1 = __expf(z1), w2 = __expf(z2), w3 = __expf(z3);
        agx[0] += w0 * xv.x; agy[0] += w0 * xv.y; agz[0] += w0 * xv.z; dn[0] += w0;
        agx[1] += w1 * xv.x; agy[1] += w1 * xv.y; agz[1] += w1 * xv.z; dn[1] += w1;
        agx[2] += w2 * xv.x; agy[2] += w2 * xv.y; agz[2] += w2 * xv.z; dn[2] += w2;
        agx[3] += w3 * xv.x; agy[3] += w3 * xv.y; agz[3] += w3 * xv.z; dn[3] += w3;
    }

#pragma unroll
    for (int h = 0; h < 4; ++h) {
        int j = h * 16 + sl;
        float inv = 1.f / (dn[h] + 1e-16f);
        float o = (agx[h] * W1[j] + agy[h] * W1[64 + j] + agz[h] * W1[128 + j]) * inv + b1[j];
        x1[(size_t)node * 64 + j] = (o > 0.f) ? o : 0.f;
    }
}

// ---------------- Layer 2: GATv2Conv(64, 16, heads=2) ----------------

__global__ __launch_bounds__(256) void k_l2_transform(const float* __restrict__ x1,
                                                      const float* __restrict__ W2l, const float* __restrict__ b2l,
                                                      const float* __restrict__ W2r, const float* __restrict__ b2r,
                                                      unsigned short* __restrict__ hlb, float* __restrict__ hr, int N) {
    __shared__ float xs[64 * 68];   // row stride 68: per-wave broadcast rows hit banks {0,4,8,12}
    int t = threadIdx.x;
    int node0 = blockIdx.x * 64;
    int nrem = N - node0; if (nrem > 64) nrem = 64;
    const float4* xg = (const float4*)x1;
#pragma unroll
    for (int it = 0; it < 4; ++it) {
        int id = it * 256 + t;
        int row = id >> 4, c4 = id & 15;
        float4 v = make_float4(0.f, 0.f, 0.f, 0.f);
        if (row < nrem) v = xg[(size_t)(node0 + row) * 16 + c4];
        *(float4*)&xs[row * 68 + c4 * 4] = v;
    }
    __syncthreads();
    int nt = t >> 4;
    int jt = t & 15;
    int jq = jt & 7;
    int jc = jq * 4;
    const float4* W4 = (const float4*)((jt < 8) ? W2l : W2r);
    const float4* B4 = (const float4*)((jt < 8) ? b2l : b2r);
    float4 bb = B4[jq];
    float4 acc[4];
#pragma unroll
    for (int i = 0; i < 4; ++i) acc[i] = bb;
#pragma unroll 2
    for (int k4 = 0; k4 < 16; ++k4) {
        float4 w0 = W4[(k4 * 4 + 0) * 8 + jq];
        float4 w1 = W4[(k4 * 4 + 1) * 8 + jq];
        float4 w2 = W4[(k4 * 4 + 2) * 8 + jq];
        float4 w3 = W4[(k4 * 4 + 3) * 8 + jq];
#pragma unroll
        for (int i = 0; i < 4; ++i) {
            float4 xv = *(const float4*)&xs[(nt + i * 16) * 68 + k4 * 4];
            acc[i].x += xv.x * w0.x + xv.y * w1.x + xv.z * w2.x + xv.w * w3.x;
            acc[i].y += xv.x * w0.y + xv.y * w1.y + xv.z * w2.y + xv.w * w3.y;
            acc[i].z += xv.x * w0.z + xv.y * w1.z + xv.z * w2.z + xv.w * w3.z;
            acc[i].w += xv.x * w0.w + xv.y * w1.w + xv.z * w2.w + xv.w * w3.w;
        }
    }
#pragma unroll
    for (int i = 0; i < 4; ++i) {
        int row = nt + i * 16;
        if (row < nrem) {
            size_t node = node0 + row;
            if (jt < 8) {
                uint2 p;
                p.x = (unsigned)f2us(acc[i].x) | ((unsigned)f2us(acc[i].y) << 16);
                p.y = (unsigned)f2us(acc[i].z) | ((unsigned)f2us(acc[i].w) << 16);
                *(uint2*)&hlb[node * 32 + jc] = p;
            } else {
                *(float4*)&hr[node * 32 + jc] = acc[i];
            }
        }
    }
}

// Edge-parallel, cooperative gather: 16 lanes/node = 4 edge slots x 4 channel-quarters.
// Each lane loads 16B (its 8-channel quarter) of the 64B hl row -> quartet shares ONE cache
// line (1 txn/edge vs 4), and per-lane state drops to hrq[8]+acc[8] (occupancy up).
__global__ __launch_bounds__(256) void k_l2_agg(const unsigned short* __restrict__ hlb, const float* __restrict__ hr,
                                                const float* __restrict__ att2, const float* __restrict__ b2,
                                                const int2* __restrict__ off2, const int* __restrict__ csr,
                                                float* __restrict__ x2, int N) {
    int tid = threadIdx.x;
    int node = blockIdx.x * 16 + (tid >> 4);
    if (node >= N) return;
    int sl = tid & 15;
    int g = sl & 3;       // channel quarter: channels 8g..8g+7 (head = g>>1)
    int slot = sl >> 2;   // edge slot 0..3

    float hrq[8], atq[8];
    {
        const float4* h4 = (const float4*)(hr + (size_t)node * 32 + g * 8);
        float4 h0 = h4[0], h1 = h4[1];
        hrq[0] = h0.x; hrq[1] = h0.y; hrq[2] = h0.z; hrq[3] = h0.w;
        hrq[4] = h1.x; hrq[5] = h1.y; hrq[6] = h1.z; hrq[7] = h1.w;
        const float4* a4 = (const float4*)(att2 + g * 8);
        float4 a0 = a4[0], a1 = a4[1];
        atq[0] = a0.x; atq[1] = a0.y; atq[2] = a0.z; atq[3] = a0.w;
        atq[4] = a1.x; atq[5] = a1.y; atq[6] = a1.z; atq[7] = a1.w;
    }

    float acc[8];
#pragma unroll
    for (int j = 0; j < 8; ++j) acc[j] = 0.f;
    float den = 0.f;

    int2 ee = off2[node];
    for (int jj = ee.x + slot; jj < ee.y; jj += 4) {
        int s = csr[jj];
        uint4 u = *(const uint4*)(hlb + (size_t)s * 32 + g * 8);
        unsigned uu[4] = {u.x, u.y, u.z, u.w};
        float hlv[8];
#pragma unroll
        for (int q = 0; q < 4; ++q) {
            hlv[2 * q]     = __uint_as_float(uu[q] << 16);
            hlv[2 * q + 1] = __uint_as_float(uu[q] & 0xFFFF0000u);
        }
        float t = 0.f;
#pragma unroll
        for (int j = 0; j < 8; ++j) {
            float e = hlv[j] + hrq[j];
            e = fmaxf(e, 0.2f * e);
            t += atq[j] * e;
        }
        t += __shfl_xor(t, 1);      // combine quarter pair -> full per-head logit
        float w = __expf(t);
        den += w;
#pragma unroll
        for (int j = 0; j < 8; ++j) acc[j] += w * hlv[j];
    }

    // self-loop: once per node, on edge slot 0 (quarter pairs 0<->1, 2<->3 both active)
    if (slot == 0) {
        uint4 u = *(const uint4*)(hlb + (size_t)node * 32 + g * 8);
        unsigned uu[4] = {u.x, u.y, u.z, u.w};
        float hlv[8];
#pragma unroll
        for (int q = 0; q < 4; ++q) {
            hlv[2 * q]     = __uint_as_float(uu[q] << 16);
            hlv[2 * q + 1] = __uint_as_float(uu[q] & 0xFFFF0000u);
        }
        float t = 0.f;
#pragma unroll
        for (int j = 0; j < 8; ++j) {
            float e = hlv[j] + hrq[j];
            e = fmaxf(e, 0.2f * e);
            t += atq[j] * e;
        }
        t += __shfl_xor(t, 1);
        float w = __expf(t);
        den += w;
#pragma unroll
        for (int j = 0; j < 8; ++j) acc[j] += w * hlv[j];
    }

    // fold over edge slots (tid bits 2,3); quarters/heads stay separate
#pragma unroll
    for (int d = 4; d <= 8; d <<= 1) {
#pragma unroll
        for (int j = 0; j < 8; ++j) acc[j] += __shfl_xor(acc[j], d);
        den += __shfl_xor(den, d);
    }

    if (slot < 2) {
        float inv = 1.f / (den + 1e-16f);
        int c = g * 8 + slot * 4;
        float4 bb = *(const float4*)(b2 + c);
        float o0 = slot ? acc[4] : acc[0];
        float o1 = slot ? acc[5] : acc[1];
        float o2 = slot ? acc[6] : acc[2];
        float o3 = slot ? acc[7] : acc[3];
        *(float4*)&x2[(size_t)node * 32 + c] =
            make_float4(o0 * inv + bb.x, o1 * inv + bb.y, o2 * inv + bb.z, o3 * inv + bb.w);
    }
}

// ---------------- Layer 3: TransformerConv(32, 7, heads=1) ----------------

__global__ __launch_bounds__(256) void k_l3_transform(const float* __restrict__ x2,
                                                      const float4* __restrict__ Wc4, const float4* __restrict__ bc4,
                                                      float* __restrict__ QS, unsigned short* __restrict__ KVb, int N) {
    __shared__ float xs[128 * 36];
    int t = threadIdx.x;
    int node0 = blockIdx.x * 128;
    int nrem = N - node0; if (nrem > 128) nrem = 128;
    const float4* xg = (const float4*)x2;
#pragma unroll
    for (int it = 0; it < 4; ++it) {
        int id = it * 256 + t;
        int row = id >> 3, c4 = id & 7;
        float4 v = make_float4(0.f, 0.f, 0.f, 0.f);
        if (row < nrem) v = xg[(size_t)(node0 + row) * 8 + c4];
        *(float4*)&xs[row * 36 + c4 * 4] = v;
    }
    __syncthreads();
    int nt = t >> 3;
    int jt = t & 7;
    float4 bb = bc4[jt];
    float4 acc[4];
#pragma unroll
    for (int i = 0; i < 4; ++i) acc[i] = bb;
#pragma unroll 2
    for (int k4 = 0; k4 < 8; ++k4) {
        float4 w0 = Wc4[(k4 * 4 + 0) * 8 + jt];
        float4 w1 = Wc4[(k4 * 4 + 1) * 8 + jt];
        float4 w2 = Wc4[(k4 * 4 + 2) * 8 + jt];
        float4 w3 = Wc4[(k4 * 4 + 3) * 8 + jt];
#pragma unroll
        for (int i = 0; i < 4; ++i) {
            float4 xv = *(const float4*)&xs[(nt + i * 32) * 36 + k4 * 4];
            acc[i].x += xv.x * w0.x + xv.y * w1.x + xv.z * w2.x + xv.w * w3.x;
            acc[i].y += xv.x * w0.y + xv.y * w1.y + xv.z * w2.y + xv.w * w3.y;
            acc[i].z += xv.x * w0.z + xv.y * w1.z + xv.z * w2.z + xv.w * w3.z;
            acc[i].w += xv.x * w0.w + xv.y * w1.w + xv.z * w2.w + xv.w * w3.w;
        }
    }
#pragma unroll
    for (int i = 0; i < 4; ++i) {
        int row = nt + i * 32;
        if (row < nrem) {
            size_t node = node0 + row;
            if (jt < 4) {
                *(float4*)(QS + node * 16 + jt * 4) = acc[i];
            } else {
                uint2 p;
                p.x = (unsigned)f2us(acc[i].x) | ((unsigned)f2us(acc[i].y) << 16);
                p.y = (unsigned)f2us(acc[i].z) | ((unsigned)f2us(acc[i].w) << 16);
                *(uint2*)&KVb[node * 16 + (size_t)(jt - 4) * 4] = p;
            }
        }
    }
}

// Edge-parallel, pair-cooperative: 16 lanes/node = 8 edge slots x 2 sides.
// side0 loads K (16B) + computes the dot; side1 loads V (16B) + accumulates w*V and denom.
// Pair shares one 64B line -> 1 txn/edge (vs 2), one gather instr per edge-pair.
__global__ __launch_bounds__(256) void k_l3_agg(const float* __restrict__ QS, const unsigned short* __restrict__ KVb,
                                                const int2* __restrict__ off2, const int* __restrict__ csr,
                                                float* __restrict__ out, int N) {
    int tid = threadIdx.x;
    int node = blockIdx.x * 16 + (tid >> 4);
    if (node >= N) return;
    int sl = tid & 15;
    int side = sl & 1;
    int p = sl >> 1;          // edge slot 0..7
    int lane = tid & 63;
    const float scale = 0.3779644730092272f;  // 1/sqrt(7)
    const float4* q4 = (const float4*)(QS + (size_t)node * 16);
    float4 qa = q4[0], qb = q4[1];
    qa.x *= scale; qa.y *= scale; qa.z *= scale; qa.w *= scale;
    qb.x *= scale; qb.y *= scale; qb.z *= scale; qb.w = 0.f;

    float v[8];
#pragma unroll
    for (int i = 0; i < 8; ++i) v[i] = 0.f;

    int2 ee = off2[node];
    for (int jj = ee.x + p; jj < ee.y; jj += 8) {
        int s = csr[jj];
        uint4 u = *(const uint4*)(KVb + (size_t)s * 16 + (side << 3));
        float t = 0.f;
        if (!side) {
            float k0 = __uint_as_float(u.x << 16), k1 = __uint_as_float(u.x & 0xFFFF0000u);
            float k2 = __uint_as_float(u.y << 16), k3 = __uint_as_float(u.y & 0xFFFF0000u);
            float k4 = __uint_as_float(u.z << 16), k5 = __uint_as_float(u.z & 0xFFFF0000u);
            float k6 = __uint_as_float(u.w << 16);
            t = qa.x * k0 + qa.y * k1 + qa.z * k2 + qa.w * k3
              + qb.x * k4 + qb.y * k5 + qb.z * k6;
        }
        float tf = __shfl_xor(t, 1);   // side1 receives side0's logit (convergent: pair shares jj)
        if (side) {
            float w = __expf(tf);
            v[0] += w * __uint_as_float(u.x << 16);
            v[1] += w * __uint_as_float(u.x & 0xFFFF0000u);
            v[2] += w * __uint_as_float(u.y << 16);
            v[3] += w * __uint_as_float(u.y & 0xFFFF0000u);
            v[4] += w * __uint_as_float(u.z << 16);
            v[5] += w * __uint_as_float(u.z & 0xFFFF0000u);
            v[6] += w * __uint_as_float(u.w << 16);
            v[7] += w;
        }
    }

    // swap-butterfly over edge-slot bits (xor distances 2,4,8); sides never mix.
    // After: side1 lane with slot p holds component p in v[0] (p=0..6 acc, p=7 denom).
#pragma unroll
    for (int d = 4; d >= 1; d >>= 1) {
#pragma unroll
        for (int i = 0; i < 8; ++i) {
            if (i < d) {
                float a = v[i], b = v[i + d];
                float send = (p & d) ? a : b;
                float recv = __shfl_xor(send, d << 1);
                v[i] = ((p & d) ? b : a) + recv;
            }
        }
    }
    float r = v[0];
    float den = __shfl(r, (lane & 48) | 15);   // side1,p=7 lane of this node's group
    if (side && p < 7) out[(size_t)node * 7 + p] = r / (den + 1e-16f)
                                                   + QS[(size_t)node * 16 + 8 + p];
}

// ---------------- launcher ----------------

extern "C" void kernel_launch(void* const* d_in, const int* in_sizes, int n_in,
                              void* d_out, int out_size, void* d_ws, size_t ws_size,
                              hipStream_t stream) {
    const int* ei = (const int*)d_in[1];
    float* out = (float*)d_out;

    int N = in_sizes[0] / 3;
    int E = in_sizes[1] / 2;
    int NB = (N + BMASK) >> BSH;        // assumed <= 512 (N <= 262144)
    int C = (E + NB - 1) / NB + 4096;   // fixed bucket capacity (mean + huge slack for random dst)

    char* ws = (char*)d_ws;
    size_t o = 0;
    auto take = [&](size_t bytes) -> char* {
        char* p = ws + o;
        o = (o + bytes + 255) & ~(size_t)255;
        return p;
    };
    int total_f = 0;
    for (int i = 2; i < 20; ++i) total_f += in_sizes[i];
    float* canon   = (float*)take((size_t)total_f * 4);
    float* Wcat    = (float*)take(32 * 32 * 4);
    float* bcat    = (float*)take(32 * 4);
    int2*  off2    = (int2*)take((size_t)N * 8);
    int*   bcur    = (int*)take(516 * 4);               // [0..511]=bucket cursors, [512]=isf32 flag
    int*   csr     = (int*)take((size_t)NB * C * 4);
    float* bufA    = (float*)take((size_t)N * 64 * 4);  // axs -> hlb|hr -> QS|KVb
    float* ad1     = (float*)take((size_t)N * 4 * 4);
    float* bufB    = (float*)take((size_t)N * 64 * 4);  // bkt -> x1 -> x2
    (void)ws_size; (void)n_in; (void)out_size;

    CvtArgs ca;
    const float* cp[20];
    {
        int off_ = 0, k = 0;
        for (int i = 0; i < 20; ++i) {
            if (i < 2) { cp[i] = nullptr; continue; }
            ca.p[k] = d_in[i];
            ca.sz[k] = in_sizes[i];
            cp[i] = canon + off_;
            off_ += in_sizes[i];
            ++k;
        }
    }

    int nbconv = (total_f + 255) / 256;
    k_convert<<<nbconv + 1, 256, 0, stream>>>(ca, (const unsigned short*)d_in[0], canon, total_f,
                                              nbconv, Wcat, bcat, bcur);
    const int* flagp = bcur + 512;

    // bkt aliases bufB (NB*C*4 ~= 9.6 MB <= N*256 B); x1 written only after k_bbuild
    int* bkt = (int*)bufB;
    int gb = (E + 4095) / 4096;
    k_bscatter<<<gb, 1024, 0, stream>>>(ei, bcur, bkt, E, NB, C);
    k_bbuild<<<NB, 512, 0, stream>>>(bkt, bcur, off2, csr, N, C);

    float* axs = bufA;                                   // N*32B interleaved {a_src[4], x[3], pad}
    k_l1_transform<<<(N + 3) / 4, 256, 0, stream>>>(d_in[0], flagp, cp[2], cp[3], cp[4], axs, ad1, N);
    float* x1 = bufB;
    k_l1_agg<<<(N + 15) / 16, 256, 0, stream>>>(axs, (const float4*)ad1, off2, csr, cp[2], cp[5], x1, N);

    unsigned short* hlb = (unsigned short*)bufA;         // N*32 bf16 = 6.4 MB
    float* hr = bufA + (size_t)N * 16;
    k_l2_transform<<<(N + 63) / 64, 256, 0, stream>>>(x1, cp[6], cp[7], cp[8], cp[9], hlb, hr, N);
    float* x2 = bufB;
    k_l2_agg<<<(N + 15) / 16, 256, 0, stream>>>(hlb, hr, cp[10], cp[11], off2, csr, x2, N);

    float* QS = bufA;                                    // N*16 floats
    unsigned short* KVb = (unsigned short*)(bufA + (size_t)N * 16);  // N*16 bf16 = 3.2 MB (L2-resident)
    k_l3_transform<<<(N + 127) / 128, 256, 0, stream>>>(x2, (const float4*)Wcat, (const float4*)bcat,
                                                        QS, KVb, N);
    k_l3_agg<<<(N + 15) / 16, 256, 0, stream>>>(QS, KVb, off2, csr, out, N);
}